// Round 3
// baseline (1027.927 us; speedup 1.0000x reference)
//
#include <hip/hip_runtime.h>
#include <math.h>

#define NLEV 44
#define IMG 178
#define NPTS (IMG*IMG)
#define HASH_SIZE 1024
#define PRIME 2654435761u

struct LevelParams {
    int res[NLEV];
    int offs[NLEV];
    unsigned long long dense_mask;
};

// launch_bounds(256, 2): VGPR cap = 256/2 = 128 (compiler budgets the
// 256-architected file). (256,4) capped at 64 -> 2.8GB scratch spill, 7x slower.
__global__ __launch_bounds__(256, 2) void shacira_kernel(
    const float* __restrict__ x, const float* __restrict__ codebook,
    const float* __restrict__ w1, const float* __restrict__ w2,
    const float* __restrict__ w3, float* __restrict__ out,
    int total, LevelParams lp)
{
    const int b = blockIdx.y;
    const int n = blockIdx.x * blockDim.x + threadIdx.x;

    __shared__ float sW1[16 * NLEV];   // layout: [l][o] (transposed at stage time)
    __shared__ float sW2[16 * 16];
    __shared__ float sW3[3 * 16];
    {
        const float* w1b = w1 + (size_t)b * 16 * NLEV;
        const float* w2b = w2 + (size_t)b * 16 * 16;
        const float* w3b = w3 + (size_t)b * 3 * 16;
        for (int i = threadIdx.x; i < 16 * NLEV; i += blockDim.x) {
            const int o = i / NLEV, l = i % NLEV;
            sW1[l * 16 + o] = w1b[i];
        }
        if (threadIdx.x < 256) sW2[threadIdx.x] = w2b[threadIdx.x];
        if (threadIdx.x < 48)  sW3[threadIdx.x] = w3b[threadIdx.x];
    }
    __syncthreads();

    if (n >= NPTS) return;

    const float2 xy = reinterpret_cast<const float2*>(x)[(size_t)b * NPTS + n];
    const float* cb = codebook + (size_t)b * total;

    float h1[16];
#pragma unroll
    for (int o = 0; o < 16; ++o) h1[o] = 0.f;

#pragma unroll
    for (int l = 0; l < NLEV; ++l) {
        const int res = lp.res[l];
        const float rf = (float)res;
        const float sx = xy.x * rf;
        const float sy = xy.y * rf;
        const float bxf = floorf(sx);
        const float byf = floorf(sy);
        const float fx = sx - bxf;
        const float fy = sy - byf;
        int ix0 = (int)bxf, iy0 = (int)byf;
        const int ix1 = min(ix0 + 1, res), iy1 = min(iy0 + 1, res);
        ix0 = min(ix0, res); iy0 = min(iy0, res);
        int i00, i01, i10, i11;
        if ((lp.dense_mask >> l) & 1ull) {
            const int st = res + 1;
            i00 = iy0 * st + ix0;
            i01 = iy1 * st + ix0;
            i10 = iy0 * st + ix1;
            i11 = iy1 * st + ix1;
        } else {
            const unsigned px0 = (unsigned)ix0, px1 = (unsigned)ix1;
            const unsigned py0 = (unsigned)iy0 * PRIME, py1 = (unsigned)iy1 * PRIME;
            i00 = (int)((px0 ^ py0) & (unsigned)(HASH_SIZE - 1));
            i01 = (int)((px0 ^ py1) & (unsigned)(HASH_SIZE - 1));
            i10 = (int)((px1 ^ py0) & (unsigned)(HASH_SIZE - 1));
            i11 = (int)((px1 ^ py1) & (unsigned)(HASH_SIZE - 1));
        }
        const float* cbl = cb + lp.offs[l];
        const float v00 = cbl[i00];
        const float v01 = cbl[i01];
        const float v10 = cbl[i10];
        const float v11 = cbl[i11];
        // 6-op bilinear lerp
        const float vx0 = fmaf(fx, v10 - v00, v00);
        const float vx1 = fmaf(fx, v11 - v01, v01);
        const float feat = fmaf(fy, vx1 - vx0, vx0);
        // fused w1 GEMV accumulate (uniform LDS broadcast reads, b128-vectorizable)
#pragma unroll
        for (int o = 0; o < 16; ++o)
            h1[o] = fmaf(feat, sW1[l * 16 + o], h1[o]);
    }

#pragma unroll
    for (int o = 0; o < 16; ++o) h1[o] = fmaxf(h1[o], 0.f);

    float h2[16];
#pragma unroll
    for (int o = 0; o < 16; ++o) {
        float acc = 0.f;
#pragma unroll
        for (int k = 0; k < 16; ++k) acc = fmaf(h1[k], sW2[o * 16 + k], acc);
        h2[o] = fmaxf(acc, 0.f);
    }
    float rgb[3];
#pragma unroll
    for (int c = 0; c < 3; ++c) {
        float acc = 0.f;
#pragma unroll
        for (int k = 0; k < 16; ++k) acc = fmaf(h2[k], sW3[c * 16 + k], acc);
        rgb[c] = 1.f / (1.f + expf(-acc));
    }
    float* op = out + ((size_t)b * NPTS + n) * 3;
    op[0] = rgb[0];
    op[1] = rgb[1];
    op[2] = rgb[2];
}

extern "C" void kernel_launch(void* const* d_in, const int* in_sizes, int n_in,
                              void* d_out, int out_size, void* d_ws, size_t ws_size,
                              hipStream_t stream) {
    const float* x        = (const float*)d_in[0];
    const float* codebook = (const float*)d_in[1];
    const float* w1       = (const float*)d_in[2];
    const float* w2       = (const float*)d_in[3];
    const float* w3       = (const float*)d_in[4];
    float* out = (float*)d_out;

    const int B = in_sizes[0] / (NPTS * 2);

    LevelParams lp;
    unsigned long long mask = 0;
    int off = 0;
    for (int l = 0; l < NLEV; ++l) {
        const double r = 16.0 * pow(128.0 / 16.0, (double)l / (double)(NLEV - 1));
        const int res = (int)llrint(r);
        lp.res[l] = res;
        lp.offs[l] = off;
        int sz;
        if ((long long)(res + 1) * (res + 1) <= HASH_SIZE) {
            mask |= (1ull << l);
            sz = (res + 1) * (res + 1);
        } else {
            sz = HASH_SIZE;
        }
        off += sz;
    }
    lp.dense_mask = mask;
    const int total = off;

    dim3 block(256);
    dim3 grid((NPTS + 255) / 256, B);
    shacira_kernel<<<grid, block, 0, stream>>>(x, codebook, w1, w2, w3, out, total, lp);
}

// Round 4
// 85.473 us; speedup vs baseline: 12.0264x; 12.0264x over previous
//
#include <hip/hip_runtime.h>
#include <math.h>

#define NLEV 44
#define IMG 178
#define NPTS (IMG*IMG)
#define HASH_SIZE 1024
#define PRIME 2654435761u

struct LevelParams {
    int res[NLEV];
    int offs[NLEV];
    unsigned long long dense_mask;
};

// No __launch_bounds__: (256,4)->64-reg cap and (256,2)->128-reg cap both
// caused GB-scale scratch spill. Let the allocator pick; bound pressure via
// partial unroll instead.
__global__ void shacira_kernel(
    const float* __restrict__ x, const float* __restrict__ codebook,
    const float* __restrict__ w1, const float* __restrict__ w2,
    const float* __restrict__ w3, float* __restrict__ out,
    int total, LevelParams lp)
{
    const int b = blockIdx.y;
    const int n = blockIdx.x * blockDim.x + threadIdx.x;

    __shared__ float sW1[16 * NLEV];   // [l][o] layout
    __shared__ float sW2[16 * 16];
    __shared__ float sW3[3 * 16];
    __shared__ float sResF[NLEV];
    __shared__ int   sOffs[NLEV];
    __shared__ int   sSt[NLEV];        // res+1 if dense, 0 if hashed
    {
        const float* w1b = w1 + (size_t)b * 16 * NLEV;
        const float* w2b = w2 + (size_t)b * 16 * 16;
        const float* w3b = w3 + (size_t)b * 3 * 16;
        for (int i = threadIdx.x; i < 16 * NLEV; i += blockDim.x) {
            const int o = i / NLEV, l = i % NLEV;
            sW1[l * 16 + o] = w1b[i];
        }
        if (threadIdx.x < 256) sW2[threadIdx.x] = w2b[threadIdx.x];
        if (threadIdx.x < 48)  sW3[threadIdx.x] = w3b[threadIdx.x];
        if (threadIdx.x < NLEV) {
            const int r = lp.res[threadIdx.x];
            sResF[threadIdx.x] = (float)r;
            sOffs[threadIdx.x] = lp.offs[threadIdx.x];
            sSt[threadIdx.x]   = ((lp.dense_mask >> threadIdx.x) & 1ull) ? (r + 1) : 0;
        }
    }
    __syncthreads();

    if (n >= NPTS) return;

    const float2 xy = reinterpret_cast<const float2*>(x)[(size_t)b * NPTS + n];
    const float* cb = codebook + (size_t)b * total;

    float h1[16];
#pragma unroll
    for (int o = 0; o < 16; ++o) h1[o] = 0.f;

#pragma unroll 4
    for (int l = 0; l < NLEV; ++l) {
        const float rf = sResF[l];
        const int st  = sSt[l];
        const int off = sOffs[l];
        const float sx = xy.x * rf;
        const float sy = xy.y * rf;
        const float bxf = floorf(sx);
        const float byf = floorf(sy);
        const float fx = sx - bxf;
        const float fy = sy - byf;
        const int res = (int)rf;
        int ix0 = (int)bxf, iy0 = (int)byf;
        const int ix1 = min(ix0 + 1, res), iy1 = min(iy0 + 1, res);
        ix0 = min(ix0, res); iy0 = min(iy0, res);
        int i00, i01, i10, i11;
        if (__builtin_amdgcn_readfirstlane(st) != 0) {   // dense level (wave-uniform)
            i00 = iy0 * st + ix0;
            i01 = iy1 * st + ix0;
            i10 = iy0 * st + ix1;
            i11 = iy1 * st + ix1;
        } else {                                          // hashed level
            const unsigned px0 = (unsigned)ix0, px1 = (unsigned)ix1;
            const unsigned py0 = (unsigned)iy0 * PRIME, py1 = (unsigned)iy1 * PRIME;
            i00 = (int)((px0 ^ py0) & (unsigned)(HASH_SIZE - 1));
            i01 = (int)((px0 ^ py1) & (unsigned)(HASH_SIZE - 1));
            i10 = (int)((px1 ^ py0) & (unsigned)(HASH_SIZE - 1));
            i11 = (int)((px1 ^ py1) & (unsigned)(HASH_SIZE - 1));
        }
        const float* cbl = cb + off;
        const float v00 = cbl[i00];
        const float v01 = cbl[i01];
        const float v10 = cbl[i10];
        const float v11 = cbl[i11];
        const float vx0 = fmaf(fx, v10 - v00, v00);
        const float vx1 = fmaf(fx, v11 - v01, v01);
        const float feat = fmaf(fy, vx1 - vx0, vx0);
#pragma unroll
        for (int o = 0; o < 16; ++o)
            h1[o] = fmaf(feat, sW1[l * 16 + o], h1[o]);
    }

#pragma unroll
    for (int o = 0; o < 16; ++o) h1[o] = fmaxf(h1[o], 0.f);

    float h2[16];
#pragma unroll
    for (int o = 0; o < 16; ++o) {
        float acc = 0.f;
#pragma unroll
        for (int k = 0; k < 16; ++k) acc = fmaf(h1[k], sW2[o * 16 + k], acc);
        h2[o] = fmaxf(acc, 0.f);
    }
    float rgb[3];
#pragma unroll
    for (int c = 0; c < 3; ++c) {
        float acc = 0.f;
#pragma unroll
        for (int k = 0; k < 16; ++k) acc = fmaf(h2[k], sW3[c * 16 + k], acc);
        rgb[c] = 1.f / (1.f + expf(-acc));
    }
    float* op = out + ((size_t)b * NPTS + n) * 3;
    op[0] = rgb[0];
    op[1] = rgb[1];
    op[2] = rgb[2];
}

extern "C" void kernel_launch(void* const* d_in, const int* in_sizes, int n_in,
                              void* d_out, int out_size, void* d_ws, size_t ws_size,
                              hipStream_t stream) {
    const float* x        = (const float*)d_in[0];
    const float* codebook = (const float*)d_in[1];
    const float* w1       = (const float*)d_in[2];
    const float* w2       = (const float*)d_in[3];
    const float* w3       = (const float*)d_in[4];
    float* out = (float*)d_out;

    const int B = in_sizes[0] / (NPTS * 2);

    LevelParams lp;
    unsigned long long mask = 0;
    int off = 0;
    for (int l = 0; l < NLEV; ++l) {
        const double r = 16.0 * pow(128.0 / 16.0, (double)l / (double)(NLEV - 1));
        const int res = (int)llrint(r);
        lp.res[l] = res;
        lp.offs[l] = off;
        int sz;
        if ((long long)(res + 1) * (res + 1) <= HASH_SIZE) {
            mask |= (1ull << l);
            sz = (res + 1) * (res + 1);
        } else {
            sz = HASH_SIZE;
        }
        off += sz;
    }
    lp.dense_mask = mask;
    const int total = off;

    dim3 block(256);
    dim3 grid((NPTS + 255) / 256, B);
    shacira_kernel<<<grid, block, 0, stream>>>(x, codebook, w1, w2, w3, out, total, lp);
}

// Round 5
// 61.327 us; speedup vs baseline: 16.7615x; 1.3937x over previous
//
#include <hip/hip_runtime.h>
#include <math.h>

#define NLEV 44
#define IMG 178
#define NPTS (IMG*IMG)
#define HASH_SIZE 1024
#define PRIME 2654435761u
#define BLOCK 1024
#define PTS_PER_BLOCK (2*BLOCK)

struct LevelParams {
    int res[NLEV];
    int offs[NLEV];
    int nDense;   // levels [0,nDense) are dense, rest hashed
    int total;    // total codebook floats per batch (38584)
};

// One 1024-thread block per CU; full per-batch codebook staged in dynamic LDS
// (~151KB). All 176 gathers/point become ds_read_b32 instead of scattered
// global loads (L1/TA was the round-4 bottleneck at ~37 cyc/wave-gather).
__global__ __launch_bounds__(BLOCK) void shacira_kernel(
    const float* __restrict__ x, const float* __restrict__ codebook,
    const float* __restrict__ w1, const float* __restrict__ w2,
    const float* __restrict__ w3, float* __restrict__ out,
    LevelParams lp)
{
    extern __shared__ float smem[];
    const int total = lp.total;
    float* sCB   = smem;               // [total]
    float* sW1   = sCB + total;        // [NLEV][16]  ([l][o] layout)
    float* sW2   = sW1 + 16 * NLEV;    // [16][16]
    float* sW3   = sW2 + 256;          // [3][16]
    float* sResF = sW3 + 48;           // [NLEV]
    int*   sOffs = (int*)(sResF + NLEV);

    const int tid = threadIdx.x;
    const int b = blockIdx.y;

    // ---- stage codebook (float4, coalesced; L2-resident source) ----
    {
        const float* cbg = codebook + (size_t)b * total;
        const float4* src = (const float4*)cbg;
        float4* dst = (float4*)sCB;
        const int n4 = total >> 2;
        for (int i = tid; i < n4; i += BLOCK) dst[i] = src[i];
        for (int i = (n4 << 2) + tid; i < total; i += BLOCK) sCB[i] = cbg[i];

        const float* w1b = w1 + (size_t)b * 16 * NLEV;
        const float* w2b = w2 + (size_t)b * 256;
        const float* w3b = w3 + (size_t)b * 48;
        if (tid < 16 * NLEV) {
            // dst linear (conflict-free writes); src transposed read
            sW1[tid] = w1b[(tid & 15) * NLEV + (tid >> 4)];
        } else if (tid < 16 * NLEV + 256) {
            sW2[tid - 16 * NLEV] = w2b[tid - 16 * NLEV];
        } else if (tid < 16 * NLEV + 256 + 48) {
            sW3[tid - (16 * NLEV + 256)] = w3b[tid - (16 * NLEV + 256)];
        }
        if (tid < NLEV) {
            sResF[tid] = (float)lp.res[tid];
            sOffs[tid] = lp.offs[tid];
        }
    }
    __syncthreads();

    const int nDense = lp.nDense;
    const int blockStart = blockIdx.x * PTS_PER_BLOCK;

#pragma unroll 1
    for (int p = 0; p < 2; ++p) {
        const int n = blockStart + p * BLOCK + tid;
        if (n >= NPTS) continue;

        const float2 xy = reinterpret_cast<const float2*>(x)[(size_t)b * NPTS + n];

        float h1[16];
#pragma unroll
        for (int o = 0; o < 16; ++o) h1[o] = 0.f;

        // ---- dense levels ----
#pragma unroll 4
        for (int l = 0; l < nDense; ++l) {
            const float rf = sResF[l];
            const int off = sOffs[l];
            const float sx = xy.x * rf;
            const float sy = xy.y * rf;
            const float bxf = floorf(sx);
            const float byf = floorf(sy);
            const float fx = sx - bxf;
            const float fy = sy - byf;
            const int res = (int)rf;
            const int st = res + 1;
            int ix0 = (int)bxf, iy0 = (int)byf;
            const int ix1 = min(ix0 + 1, res), iy1 = min(iy0 + 1, res);
            ix0 = min(ix0, res); iy0 = min(iy0, res);
            const int r0 = off + iy0 * st;
            const int r1 = off + iy1 * st;
            const float v00 = sCB[r0 + ix0];
            const float v01 = sCB[r1 + ix0];
            const float v10 = sCB[r0 + ix1];
            const float v11 = sCB[r1 + ix1];
            const float vx0 = fmaf(fx, v10 - v00, v00);
            const float vx1 = fmaf(fx, v11 - v01, v01);
            const float feat = fmaf(fy, vx1 - vx0, vx0);
#pragma unroll
            for (int o = 0; o < 16; ++o)
                h1[o] = fmaf(feat, sW1[l * 16 + o], h1[o]);
        }

        // ---- hashed levels ----
#pragma unroll 4
        for (int l = nDense; l < NLEV; ++l) {
            const float rf = sResF[l];
            const int off = sOffs[l];
            const float sx = xy.x * rf;
            const float sy = xy.y * rf;
            const float bxf = floorf(sx);
            const float byf = floorf(sy);
            const float fx = sx - bxf;
            const float fy = sy - byf;
            const int res = (int)rf;
            int ix0 = (int)bxf, iy0 = (int)byf;
            const int ix1 = min(ix0 + 1, res), iy1 = min(iy0 + 1, res);
            ix0 = min(ix0, res); iy0 = min(iy0, res);
            const unsigned px0 = (unsigned)ix0, px1 = (unsigned)ix1;
            const unsigned py0 = (unsigned)iy0 * PRIME, py1 = (unsigned)iy1 * PRIME;
            const int i00 = (int)((px0 ^ py0) & (HASH_SIZE - 1));
            const int i01 = (int)((px0 ^ py1) & (HASH_SIZE - 1));
            const int i10 = (int)((px1 ^ py0) & (HASH_SIZE - 1));
            const int i11 = (int)((px1 ^ py1) & (HASH_SIZE - 1));
            const float v00 = sCB[off + i00];
            const float v01 = sCB[off + i01];
            const float v10 = sCB[off + i10];
            const float v11 = sCB[off + i11];
            const float vx0 = fmaf(fx, v10 - v00, v00);
            const float vx1 = fmaf(fx, v11 - v01, v01);
            const float feat = fmaf(fy, vx1 - vx0, vx0);
#pragma unroll
            for (int o = 0; o < 16; ++o)
                h1[o] = fmaf(feat, sW1[l * 16 + o], h1[o]);
        }

#pragma unroll
        for (int o = 0; o < 16; ++o) h1[o] = fmaxf(h1[o], 0.f);

        float h2[16];
#pragma unroll
        for (int o = 0; o < 16; ++o) {
            float acc = 0.f;
#pragma unroll
            for (int k = 0; k < 16; ++k) acc = fmaf(h1[k], sW2[o * 16 + k], acc);
            h2[o] = fmaxf(acc, 0.f);
        }
        float rgb[3];
#pragma unroll
        for (int c = 0; c < 3; ++c) {
            float acc = 0.f;
#pragma unroll
            for (int k = 0; k < 16; ++k) acc = fmaf(h2[k], sW3[c * 16 + k], acc);
            rgb[c] = 1.f / (1.f + expf(-acc));
        }
        float* op = out + ((size_t)b * NPTS + n) * 3;
        op[0] = rgb[0];
        op[1] = rgb[1];
        op[2] = rgb[2];
    }
}

extern "C" void kernel_launch(void* const* d_in, const int* in_sizes, int n_in,
                              void* d_out, int out_size, void* d_ws, size_t ws_size,
                              hipStream_t stream) {
    const float* x        = (const float*)d_in[0];
    const float* codebook = (const float*)d_in[1];
    const float* w1       = (const float*)d_in[2];
    const float* w2       = (const float*)d_in[3];
    const float* w3       = (const float*)d_in[4];
    float* out = (float*)d_out;

    const int B = in_sizes[0] / (NPTS * 2);

    LevelParams lp;
    int off = 0;
    int nDense = 0;
    for (int l = 0; l < NLEV; ++l) {
        const double r = 16.0 * pow(128.0 / 16.0, (double)l / (double)(NLEV - 1));
        const int res = (int)llrint(r);
        lp.res[l] = res;
        lp.offs[l] = off;
        int sz;
        if ((long long)(res + 1) * (res + 1) <= HASH_SIZE) {
            sz = (res + 1) * (res + 1);
            nDense = l + 1;   // dense levels are a prefix (res is monotonic)
        } else {
            sz = HASH_SIZE;
        }
        off += sz;
    }
    lp.nDense = nDense;
    lp.total = off;

    const size_t smemBytes =
        ((size_t)lp.total + 16 * NLEV + 256 + 48 + NLEV) * 4 + NLEV * 4;

    hipFuncSetAttribute((const void*)shacira_kernel,
                        hipFuncAttributeMaxDynamicSharedMemorySize,
                        (int)smemBytes);

    dim3 block(BLOCK);
    dim3 grid((NPTS + PTS_PER_BLOCK - 1) / PTS_PER_BLOCK, B);
    shacira_kernel<<<grid, block, smemBytes, stream>>>(x, codebook, w1, w2, w3, out, lp);
}

// Round 6
// 51.374 us; speedup vs baseline: 20.0088x; 1.1937x over previous
//
#include <hip/hip_runtime.h>
#include <math.h>

#define NLEV 44
#define IMG 178
#define NPTS (IMG*IMG)
#define HASH_SIZE 1024
#define PRIME 2654435761u
#define BLOCK 1024
#define PTS_PER_BLOCK (2*BLOCK)

typedef __attribute__((ext_vector_type(2))) float f32x2;

struct LevelParams {
    int res[NLEV];
    int offs[NLEV];
    int nDense;   // levels [0,nDense) are dense, rest hashed
    int total;    // total codebook floats per batch
};

// acc (f32x2) += a * b, b from VGPR pair
#define PKFMA_V(acc, a, b) \
    asm("v_pk_fma_f32 %0, %1, %2, %0" : "+v"(acc) : "v"(a), "v"(b))
// acc (f32x2) += a * b, b from SGPR pair (wave-uniform weight)
#define PKFMA_S(acc, a, b) \
    asm("v_pk_fma_f32 %0, %1, %2, %0" : "+v"(acc) : "v"(a), "s"(b))

__global__ __launch_bounds__(BLOCK) void shacira_kernel(
    const float* __restrict__ x, const float* __restrict__ codebook,
    const float* __restrict__ w1, const float* __restrict__ w2,
    const float* __restrict__ w3, float* __restrict__ out,
    LevelParams lp)
{
    extern __shared__ float smem[];
    const int total = lp.total;
    float* sCB   = smem;               // [total] codebook
    float* sW1   = sCB + total;        // [NLEV][16] (transposed, [l][o])
    float* sResF = sW1 + 16 * NLEV;    // [NLEV]
    int*   sOffs = (int*)(sResF + NLEV);

    const int tid = threadIdx.x;
    const int b = blockIdx.y;

    // ---- stage codebook (float4, coalesced) + transposed W1 + tables ----
    {
        const float* cbg = codebook + (size_t)b * total;
        const float4* src = (const float4*)cbg;
        float4* dst = (float4*)sCB;
        const int n4 = total >> 2;
        for (int i = tid; i < n4; i += BLOCK) dst[i] = src[i];
        for (int i = (n4 << 2) + tid; i < total; i += BLOCK) sCB[i] = cbg[i];

        const float* w1b = w1 + (size_t)b * 16 * NLEV;
        if (tid < 16 * NLEV)
            sW1[tid] = w1b[(tid & 15) * NLEV + (tid >> 4)];  // [l][o] <- [o][l]
        if (tid < NLEV) {
            sResF[tid] = (float)lp.res[tid];
            sOffs[tid] = lp.offs[tid];
        }
    }
    __syncthreads();

    // wave-uniform global weight pointers -> s_load path (SMEM pipe)
    const float* w2b = w2 + (size_t)b * 256;
    const float* w3b = w3 + (size_t)b * 48;

    const int nDense = lp.nDense;
    const int blockStart = blockIdx.x * PTS_PER_BLOCK;

#pragma unroll 1
    for (int p = 0; p < 2; ++p) {
        const int n = blockStart + p * BLOCK + tid;
        if (n >= NPTS) continue;

        const float2 xy = reinterpret_cast<const float2*>(x)[(size_t)b * NPTS + n];

        f32x2 h1v[8];
#pragma unroll
        for (int j = 0; j < 8; ++j) { h1v[j].x = 0.f; h1v[j].y = 0.f; }

        // ---- dense levels ----
#pragma unroll 4
        for (int l = 0; l < nDense; ++l) {
            const float rf = sResF[l];
            const int off = sOffs[l];
            const float sx = xy.x * rf;
            const float sy = xy.y * rf;
            const float bxf = floorf(sx);
            const float byf = floorf(sy);
            const float fx = sx - bxf;
            const float fy = sy - byf;
            const int res = (int)rf;
            const int st = res + 1;
            const int ix0 = (int)bxf, iy0 = (int)byf;       // x in [0,1): no clamp needed
            const int ix1 = min(ix0 + 1, res), iy1 = min(iy0 + 1, res);
            const int r0 = off + iy0 * st;
            const int r1 = off + iy1 * st;
            const float v00 = sCB[r0 + ix0];
            const float v01 = sCB[r1 + ix0];
            const float v10 = sCB[r0 + ix1];
            const float v11 = sCB[r1 + ix1];
            const float vx0 = fmaf(fx, v10 - v00, v00);
            const float vx1 = fmaf(fx, v11 - v01, v01);
            const float feat = fmaf(fy, vx1 - vx0, vx0);
            f32x2 f2; f2.x = feat; f2.y = feat;
            const f32x2* wv = (const f32x2*)(sW1 + l * 16);
#pragma unroll
            for (int j = 0; j < 8; ++j) {
                const f32x2 w = wv[j];
                PKFMA_V(h1v[j], f2, w);
            }
        }

        // ---- hashed levels ----
#pragma unroll 4
        for (int l = nDense; l < NLEV; ++l) {
            const float rf = sResF[l];
            const int off = sOffs[l];
            const float sx = xy.x * rf;
            const float sy = xy.y * rf;
            const float bxf = floorf(sx);
            const float byf = floorf(sy);
            const float fx = sx - bxf;
            const float fy = sy - byf;
            const int res = (int)rf;
            const int ix0 = (int)bxf, iy0 = (int)byf;
            const int ix1 = min(ix0 + 1, res), iy1 = min(iy0 + 1, res);
            const unsigned px0 = (unsigned)ix0, px1 = (unsigned)ix1;
            const unsigned py0 = (unsigned)iy0 * PRIME, py1 = (unsigned)iy1 * PRIME;
            const int i00 = (int)((px0 ^ py0) & (HASH_SIZE - 1));
            const int i01 = (int)((px0 ^ py1) & (HASH_SIZE - 1));
            const int i10 = (int)((px1 ^ py0) & (HASH_SIZE - 1));
            const int i11 = (int)((px1 ^ py1) & (HASH_SIZE - 1));
            const float v00 = sCB[off + i00];
            const float v01 = sCB[off + i01];
            const float v10 = sCB[off + i10];
            const float v11 = sCB[off + i11];
            const float vx0 = fmaf(fx, v10 - v00, v00);
            const float vx1 = fmaf(fx, v11 - v01, v01);
            const float feat = fmaf(fy, vx1 - vx0, vx0);
            f32x2 f2; f2.x = feat; f2.y = feat;
            const f32x2* wv = (const f32x2*)(sW1 + l * 16);
#pragma unroll
            for (int j = 0; j < 8; ++j) {
                const f32x2 w = wv[j];
                PKFMA_V(h1v[j], f2, w);
            }
        }

        // relu(h1)
#pragma unroll
        for (int j = 0; j < 8; ++j) {
            h1v[j].x = fmaxf(h1v[j].x, 0.f);
            h1v[j].y = fmaxf(h1v[j].y, 0.f);
        }

        // ---- MLP2: h2[o] = relu(sum_k h1[k]*W2[o][k]), packed over k,
        //      weights stay in SGPRs (uniform s_load) ----
        float h2[16];
#pragma unroll
        for (int o = 0; o < 16; ++o) {
            const f32x2* w2v = (const f32x2*)(w2b + o * 16);
            f32x2 acc; acc.x = 0.f; acc.y = 0.f;
#pragma unroll
            for (int k = 0; k < 8; ++k) {
                const f32x2 w = w2v[k];
                PKFMA_S(acc, h1v[k], w);
            }
            h2[o] = fmaxf(acc.x + acc.y, 0.f);
        }

        f32x2 h2v[8];
#pragma unroll
        for (int j = 0; j < 8; ++j) { h2v[j].x = h2[2*j]; h2v[j].y = h2[2*j+1]; }

        // ---- MLP3 + sigmoid ----
        float rgb[3];
#pragma unroll
        for (int c = 0; c < 3; ++c) {
            const f32x2* w3v = (const f32x2*)(w3b + c * 16);
            f32x2 acc; acc.x = 0.f; acc.y = 0.f;
#pragma unroll
            for (int k = 0; k < 8; ++k) {
                const f32x2 w = w3v[k];
                PKFMA_S(acc, h2v[k], w);
            }
            const float z = acc.x + acc.y;
            rgb[c] = 1.f / (1.f + expf(-z));
        }

        float* op = out + ((size_t)b * NPTS + n) * 3;
        op[0] = rgb[0];
        op[1] = rgb[1];
        op[2] = rgb[2];
    }
}

extern "C" void kernel_launch(void* const* d_in, const int* in_sizes, int n_in,
                              void* d_out, int out_size, void* d_ws, size_t ws_size,
                              hipStream_t stream) {
    const float* x        = (const float*)d_in[0];
    const float* codebook = (const float*)d_in[1];
    const float* w1       = (const float*)d_in[2];
    const float* w2       = (const float*)d_in[3];
    const float* w3       = (const float*)d_in[4];
    float* out = (float*)d_out;

    const int B = in_sizes[0] / (NPTS * 2);

    LevelParams lp;
    int off = 0;
    int nDense = 0;
    for (int l = 0; l < NLEV; ++l) {
        const double r = 16.0 * pow(128.0 / 16.0, (double)l / (double)(NLEV - 1));
        const int res = (int)llrint(r);
        lp.res[l] = res;
        lp.offs[l] = off;
        int sz;
        if ((long long)(res + 1) * (res + 1) <= HASH_SIZE) {
            sz = (res + 1) * (res + 1);
            nDense = l + 1;   // dense levels are a prefix (res monotonic)
        } else {
            sz = HASH_SIZE;
        }
        off += sz;
    }
    lp.nDense = nDense;
    lp.total = off;

    const size_t smemBytes = ((size_t)lp.total + 16 * NLEV + 2 * NLEV) * 4;

    hipFuncSetAttribute((const void*)shacira_kernel,
                        hipFuncAttributeMaxDynamicSharedMemorySize,
                        (int)smemBytes);

    dim3 block(BLOCK);
    dim3 grid((NPTS + PTS_PER_BLOCK - 1) / PTS_PER_BLOCK, B);
    shacira_kernel<<<grid, block, smemBytes, stream>>>(x, codebook, w1, w2, w3, out, lp);
}

// Round 7
// 39.511 us; speedup vs baseline: 26.0165x; 1.3002x over previous
//
#include <hip/hip_runtime.h>
#include <math.h>

#define NLEV 44
#define NDENSE 15          // levels 0..14 dense ((res+1)^2 <= 1024); host-verified
#define IMG 178
#define NPTS (IMG*IMG)
#define HASH_SIZE 1024
#define PRIME 2654435761u
#define BLOCK 1024
#define PTS_PER_BLOCK (2*BLOCK)

typedef __attribute__((ext_vector_type(2))) float f32x2;

struct LevelParams {
    int res[NLEV];
    int offs[NLEV];
    int total;
};

// acc (f32x2) += a * b, b wave-uniform (SGPR pair)
#define PKFMA_S(acc, a, b) \
    asm("v_pk_fma_f32 %0, %1, %2, %0" : "+v"(acc) : "v"(a), "s"(b))

// ---- pre-kernel: transpose W1 [b][o][l] -> [b][l][o] into d_ws ----
__global__ __launch_bounds__(1024) void transpose_w1(const float* __restrict__ w1,
                                                     float* __restrict__ w1t) {
    const int b = blockIdx.x;
    const int i = threadIdx.x;          // i = l*16 + o
    if (i < 16 * NLEV) {
        const int l = i >> 4, o = i & 15;
        w1t[(size_t)b * 16 * NLEV + i] = w1[(size_t)b * 16 * NLEV + o * NLEV + l];
    }
}

template<bool TP>
__global__ __launch_bounds__(BLOCK) void shacira_kernel(
    const float* __restrict__ x, const float* __restrict__ codebook,
    const float* __restrict__ w1, const float* __restrict__ w1t,
    const float* __restrict__ w2, const float* __restrict__ w3,
    float* __restrict__ out, LevelParams lp)
{
    extern __shared__ float sCB[];      // codebook only (~151 KB)
    const int total = lp.total;
    const int tid = threadIdx.x;
    const int b = blockIdx.y;

    // ---- stage codebook (float4, coalesced) ----
    {
        const float* cbg = codebook + (size_t)b * total;
        const float4* src = (const float4*)cbg;
        float4* dst = (float4*)sCB;
        const int n4 = total >> 2;
        for (int i = tid; i < n4; i += BLOCK) dst[i] = src[i];
        for (int i = (n4 << 2) + tid; i < total; i += BLOCK) sCB[i] = cbg[i];
    }
    __syncthreads();

    const float* w1b = TP ? (w1t + (size_t)b * 16 * NLEV) : (w1 + (size_t)b * 16 * NLEV);
    const float* w2b = w2 + (size_t)b * 256;
    const float* w3b = w3 + (size_t)b * 48;

    const int n0 = blockIdx.x * PTS_PER_BLOCK + tid;
    const int n1 = n0 + BLOCK;
    const bool valid0 = n0 < NPTS;
    const bool valid1 = n1 < NPTS;
    const float2* xg = (const float2*)x + (size_t)b * NPTS;
    float2 xy0 = valid0 ? xg[n0] : make_float2(0.f, 0.f);
    float2 xy1 = valid1 ? xg[n1] : make_float2(0.f, 0.f);

    f32x2 h1a[8], h1b[8];
#pragma unroll
    for (int j = 0; j < 8; ++j) {
        h1a[j].x = 0.f; h1a[j].y = 0.f;
        h1b[j].x = 0.f; h1b[j].y = 0.f;
    }

    // ---- dense levels (fully unrolled; scalars from kernarg SGPRs) ----
#pragma unroll
    for (int l = 0; l < NDENSE; ++l) {
        const int res = lp.res[l];
        const int st  = res + 1;
        const int off = lp.offs[l];
        const float rf = (float)res;
        f32x2 wlv[8];
        if constexpr (TP) {
            const f32x2* wp = (const f32x2*)(w1b + l * 16);
#pragma unroll
            for (int j = 0; j < 8; ++j) wlv[j] = wp[j];
        } else {
#pragma unroll
            for (int j = 0; j < 8; ++j) {
                wlv[j].x = w1b[(2 * j) * NLEV + l];
                wlv[j].y = w1b[(2 * j + 1) * NLEV + l];
            }
        }
        auto dolevel = [&](const float2 xy, f32x2* h1) {
            const float sx = xy.x * rf, sy = xy.y * rf;
            const int ix0 = (int)sx, iy0 = (int)sy;       // x in [0,1): trunc==floor, no clamp needed
            const float fx = sx - (float)ix0, fy = sy - (float)iy0;
            const int r0 = off + iy0 * st + ix0;
            const float v00 = sCB[r0],      v10 = sCB[r0 + 1];       // ds_read2_b32
            const float v01 = sCB[r0 + st], v11 = sCB[r0 + st + 1];  // ds_read2_b32
            const float vx0 = fmaf(fx, v10 - v00, v00);
            const float vx1 = fmaf(fx, v11 - v01, v01);
            const float feat = fmaf(fy, vx1 - vx0, vx0);
            f32x2 f2; f2.x = feat; f2.y = feat;
#pragma unroll
            for (int j = 0; j < 8; ++j) PKFMA_S(h1[j], f2, wlv[j]);
        };
        dolevel(xy0, h1a);
        dolevel(xy1, h1b);
    }

    // ---- hashed levels ----
#pragma unroll
    for (int l = NDENSE; l < NLEV; ++l) {
        const int res = lp.res[l];
        const int off = lp.offs[l];
        const float rf = (float)res;
        f32x2 wlv[8];
        if constexpr (TP) {
            const f32x2* wp = (const f32x2*)(w1b + l * 16);
#pragma unroll
            for (int j = 0; j < 8; ++j) wlv[j] = wp[j];
        } else {
#pragma unroll
            for (int j = 0; j < 8; ++j) {
                wlv[j].x = w1b[(2 * j) * NLEV + l];
                wlv[j].y = w1b[(2 * j + 1) * NLEV + l];
            }
        }
        auto dolevel = [&](const float2 xy, f32x2* h1) {
            const float sx = xy.x * rf, sy = xy.y * rf;
            const int ix0 = (int)sx, iy0 = (int)sy;
            const float fx = sx - (float)ix0, fy = sy - (float)iy0;
            const unsigned px0 = (unsigned)ix0, px1 = px0 + 1u;
            const unsigned py0 = (unsigned)iy0 * PRIME, py1 = py0 + PRIME;
            const int i00 = (int)((px0 ^ py0) & (HASH_SIZE - 1));
            const int i01 = (int)((px0 ^ py1) & (HASH_SIZE - 1));
            const int i10 = (int)((px1 ^ py0) & (HASH_SIZE - 1));
            const int i11 = (int)((px1 ^ py1) & (HASH_SIZE - 1));
            const float v00 = sCB[off + i00];
            const float v01 = sCB[off + i01];
            const float v10 = sCB[off + i10];
            const float v11 = sCB[off + i11];
            const float vx0 = fmaf(fx, v10 - v00, v00);
            const float vx1 = fmaf(fx, v11 - v01, v01);
            const float feat = fmaf(fy, vx1 - vx0, vx0);
            f32x2 f2; f2.x = feat; f2.y = feat;
#pragma unroll
            for (int j = 0; j < 8; ++j) PKFMA_S(h1[j], f2, wlv[j]);
        };
        dolevel(xy0, h1a);
        dolevel(xy1, h1b);
    }

    // ---- MLP (per point) ----
    auto mlp = [&](f32x2* h1, int n, bool valid) {
        if (!valid) return;
#pragma unroll
        for (int j = 0; j < 8; ++j) {
            h1[j].x = fmaxf(h1[j].x, 0.f);
            h1[j].y = fmaxf(h1[j].y, 0.f);
        }
        float h2[16];
#pragma unroll
        for (int o = 0; o < 16; ++o) {
            const f32x2* w2v = (const f32x2*)(w2b + o * 16);
            f32x2 acc; acc.x = 0.f; acc.y = 0.f;
#pragma unroll
            for (int k = 0; k < 8; ++k) PKFMA_S(acc, h1[k], w2v[k]);
            h2[o] = fmaxf(acc.x + acc.y, 0.f);
        }
        f32x2 h2v[8];
#pragma unroll
        for (int j = 0; j < 8; ++j) { h2v[j].x = h2[2 * j]; h2v[j].y = h2[2 * j + 1]; }
        float rgb[3];
#pragma unroll
        for (int c = 0; c < 3; ++c) {
            const f32x2* w3v = (const f32x2*)(w3b + c * 16);
            f32x2 acc; acc.x = 0.f; acc.y = 0.f;
#pragma unroll
            for (int k = 0; k < 8; ++k) PKFMA_S(acc, h2v[k], w3v[k]);
            rgb[c] = 1.f / (1.f + expf(-(acc.x + acc.y)));
        }
        float* op = out + ((size_t)b * NPTS + n) * 3;
        op[0] = rgb[0]; op[1] = rgb[1]; op[2] = rgb[2];
    };
    mlp(h1a, n0, valid0);
    mlp(h1b, n1, valid1);
}

extern "C" void kernel_launch(void* const* d_in, const int* in_sizes, int n_in,
                              void* d_out, int out_size, void* d_ws, size_t ws_size,
                              hipStream_t stream) {
    const float* x        = (const float*)d_in[0];
    const float* codebook = (const float*)d_in[1];
    const float* w1       = (const float*)d_in[2];
    const float* w2       = (const float*)d_in[3];
    const float* w3       = (const float*)d_in[4];
    float* out = (float*)d_out;

    const int B = in_sizes[0] / (NPTS * 2);

    LevelParams lp;
    int off = 0;
    for (int l = 0; l < NLEV; ++l) {
        const double r = 16.0 * pow(128.0 / 16.0, (double)l / (double)(NLEV - 1));
        const int res = (int)llrint(r);
        lp.res[l] = res;
        lp.offs[l] = off;
        const int sz = ((long long)(res + 1) * (res + 1) <= HASH_SIZE)
                           ? (res + 1) * (res + 1) : HASH_SIZE;
        off += sz;
    }
    lp.total = off;

    const size_t smemBytes = (size_t)lp.total * 4;
    const size_t w1tBytes = (size_t)B * 16 * NLEV * 4;
    const bool tp = ws_size >= w1tBytes;

    if (tp) {
        transpose_w1<<<dim3(B), dim3(1024), 0, stream>>>(w1, (float*)d_ws);
        hipFuncSetAttribute((const void*)shacira_kernel<true>,
                            hipFuncAttributeMaxDynamicSharedMemorySize, (int)smemBytes);
        dim3 grid((NPTS + PTS_PER_BLOCK - 1) / PTS_PER_BLOCK, B);
        shacira_kernel<true><<<grid, dim3(BLOCK), smemBytes, stream>>>(
            x, codebook, w1, (const float*)d_ws, w2, w3, out, lp);
    } else {
        hipFuncSetAttribute((const void*)shacira_kernel<false>,
                            hipFuncAttributeMaxDynamicSharedMemorySize, (int)smemBytes);
        dim3 grid((NPTS + PTS_PER_BLOCK - 1) / PTS_PER_BLOCK, B);
        shacira_kernel<false><<<grid, dim3(BLOCK), smemBytes, stream>>>(
            x, codebook, w1, (const float*)0, w2, w3, out, lp);
    }
}